// Round 4
// baseline (335.429 us; speedup 1.0000x reference)
//
#include <hip/hip_runtime.h>

typedef float    f32x4 __attribute__((ext_vector_type(4)));
typedef short    s16x8 __attribute__((ext_vector_type(8)));
typedef short    s16x4 __attribute__((ext_vector_type(4)));
typedef unsigned u32x4 __attribute__((ext_vector_type(4)));

static __device__ __forceinline__ short f2b(float f) {
  unsigned u = __builtin_bit_cast(unsigned, f);
  u += 0x7fffu + ((u >> 16) & 1u);   // round-to-nearest-even
  return (short)(u >> 16);
}

// ---- problem constants ----
constexpr int kC  = 256;   // channels
constexpr int kN  = 49;    // tokens per window
constexpr int kNP = 64;    // padded tokens
constexpr float kScale = 0.17677669529663687f;  // 1/sqrt(32)

// Swizzled LDS offset (in shorts) for the [64 tokens][256 chan] bf16 tile.
static __device__ __forceinline__ int xoff(int n, int c) {
  return n * 256 + ((((c >> 3) ^ (n & 31)) << 3) | (c & 7));
}

// ws: Wq bf16 [768][256] @0, Wp bf16 [256][256] @393216, bxT f32 [8][64][64] @524288
__global__ void prep_kernel(const float* __restrict__ qw,
                            const float* __restrict__ pw,
                            const float* __restrict__ bt,
                            const int* __restrict__ ri,
                            short* __restrict__ Wq,
                            short* __restrict__ Wp,
                            float* __restrict__ bxT) {
  int i = blockIdx.x * 256 + threadIdx.x;
  if (i < 768 * 256) Wq[i] = f2b(qw[i]);
  if (i < 256 * 256) Wp[i] = f2b(pw[i]);
  if (i < 8 * 64 * 64) {                  // bxT[h][key][q], padding masked
    int h = i >> 12, k = (i >> 6) & 63, q = i & 63;
    float v = -10000.f;
    if (q < kN && k < kN) v = bt[ri[q * kN + k] * 8 + h];
    bxT[i] = v;
  }
}

// Build an MFMA A/B fragment (8 bf16, elem idx e = lg*8+j over a 32-block) from
// two f32x4 acc tiles: Ta holds elems 0..15, Tb 16..31, source layout
// elem = src_lg*4 + r at fixed ln.  (T12-style cvt_pk + lane shuffle.)
static __device__ __forceinline__ s16x8 fragize(f32x4 Ta, f32x4 Tb, int hi, int srcbase) {
  unsigned a0, a1, b0, b1;
  asm("v_cvt_pk_bf16_f32 %0, %1, %2" : "=v"(a0) : "v"(Ta[0]), "v"(Ta[1]));
  asm("v_cvt_pk_bf16_f32 %0, %1, %2" : "=v"(a1) : "v"(Ta[2]), "v"(Ta[3]));
  asm("v_cvt_pk_bf16_f32 %0, %1, %2" : "=v"(b0) : "v"(Tb[0]), "v"(Tb[1]));
  asm("v_cvt_pk_bf16_f32 %0, %1, %2" : "=v"(b1) : "v"(Tb[2]), "v"(Tb[3]));
  u32x4 fw;
#pragma unroll
  for (int j = 0; j < 4; ++j) {
    const int src = srcbase + (j >> 1) * 16;
    unsigned wa = __shfl((j & 1) ? a1 : a0, src);
    unsigned wb = __shfl((j & 1) ? b1 : b0, src);
    fw[j] = hi ? wb : wa;
  }
  return __builtin_bit_cast(s16x8, fw);
}

__global__ __launch_bounds__(512, 4) void winattn_kernel(
    const float* __restrict__ x, const float* __restrict__ qkv_b,
    const float* __restrict__ proj_b, const short* __restrict__ Wq,
    const short* __restrict__ Wp, const float* __restrict__ bxT,
    float* __restrict__ out) {
  __shared__ alignas(16) short xT[kNP * kC];   // 32768 B; reused as aoT in phase 3b-4
  short* aoT = xT;

  const int tid  = threadIdx.x;
  const int wv   = tid >> 6;           // wave = head
  const int lane = tid & 63;
  const int lg   = lane >> 4;
  const int ln   = lane & 15;
  const int hi   = lg >> 1;
  const int srcbase = (lg & 1) * 32 + ln;
  const size_t wbase = (size_t)blockIdx.x * (kC * kN);

  // ---------- Phase 1: stage x^T (bf16, swizzled) ----------
  {
    const float* xw = x + wbase;
    for (int i = tid; i < kC * kN; i += 512) {
      int c = i / kN, n = i - c * kN;
      xT[xoff(n, c)] = f2b(xw[i]);
    }
    for (int i = tid; i < (kNP - kN) * kC; i += 512) {
      int n = kN + (i >> 8), c = i & 255;
      xT[xoff(n, c)] = 0;
    }
  }
  __syncthreads();

  // ---------- Phase 2: per-head v (swapped), k, q (orig) -> register fragments ----------
  s16x8 Vf[2][2];    // V^T frags [dt][k2]: row d, k-elems = tokens
  s16x8 Kf[4], Qf[4];

  {  // --- V section (first: nothing else held yet)
    f32x4 accv[4][2] = {};
    const short* WA = Wq + (size_t)(512 + 32 * wv + ln) * kC + lg * 8;
    const short* WB = WA + 16 * kC;
#pragma unroll
    for (int kk = 0; kk < 8; ++kk) {
      const s16x8 A0 = *(const s16x8*)&WA[kk * 32];
      const s16x8 A1 = *(const s16x8*)&WB[kk * 32];
#pragma unroll
      for (int tt = 0; tt < 4; ++tt) {
        const s16x8 B = *(const s16x8*)&xT[xoff(tt * 16 + ln, kk * 32 + lg * 8)];
        accv[tt][0] = __builtin_amdgcn_mfma_f32_16x16x32_bf16(B, A0, accv[tt][0], 0, 0, 0);
        accv[tt][1] = __builtin_amdgcn_mfma_f32_16x16x32_bf16(B, A1, accv[tt][1], 0, 0, 0);
      }
    }
    const float bv0 = qkv_b[512 + 32 * wv + ln];
    const float bv1 = qkv_b[512 + 32 * wv + 16 + ln];
#pragma unroll
    for (int dt = 0; dt < 2; ++dt) {
      const float bv = dt ? bv1 : bv0;
#pragma unroll
      for (int k2 = 0; k2 < 2; ++k2) {
        f32x4 Ta, Tb;
#pragma unroll
        for (int r = 0; r < 4; ++r) {
          Ta[r] = accv[2 * k2][dt][r] + bv;
          Tb[r] = accv[2 * k2 + 1][dt][r] + bv;
        }
        Vf[dt][k2] = fragize(Ta, Tb, hi, srcbase);
      }
    }
  }
  __builtin_amdgcn_sched_barrier(0);

#pragma unroll 1
  for (int t = 1; t >= 0; --t) {   // --- K section (t=1), then Q section (t=0)
    f32x4 acc0[4] = {}, acc1[4] = {};
    const short* WA = Wq + (size_t)(t * 256 + 32 * wv + ln) * kC + lg * 8;
    const short* WB = WA + 16 * kC;
#pragma unroll
    for (int kk = 0; kk < 8; ++kk) {
      const s16x8 A0 = *(const s16x8*)&WA[kk * 32];
      const s16x8 A1 = *(const s16x8*)&WB[kk * 32];
#pragma unroll
      for (int nt = 0; nt < 4; ++nt) {
        const s16x8 B = *(const s16x8*)&xT[xoff(nt * 16 + ln, kk * 32 + lg * 8)];
        acc0[nt] = __builtin_amdgcn_mfma_f32_16x16x32_bf16(A0, B, acc0[nt], 0, 0, 0);
        acc1[nt] = __builtin_amdgcn_mfma_f32_16x16x32_bf16(A1, B, acc1[nt], 0, 0, 0);
      }
    }
    const int rb = t * 256 + 32 * wv;
    const f32x4 b0 = *(const f32x4*)&qkv_b[rb + lg * 4];
    const f32x4 b1 = *(const f32x4*)&qkv_b[rb + 16 + lg * 4];
    const float sc = t ? 1.f : kScale;
#pragma unroll
    for (int nt = 0; nt < 4; ++nt) {
      f32x4 Ta, Tb;
#pragma unroll
      for (int r = 0; r < 4; ++r) {
        Ta[r] = (acc0[nt][r] + b0[r]) * sc;
        Tb[r] = (acc1[nt][r] + b1[r]) * sc;
      }
      if (t) Kf[nt] = fragize(Ta, Tb, hi, srcbase);
      else   Qf[nt] = fragize(Ta, Tb, hi, srcbase);
    }
    __builtin_amdgcn_sched_barrier(0);
  }
  __syncthreads();   // all x^T reads done -> region reusable as aoT
  __builtin_amdgcn_sched_barrier(0);

  // ---------- Phase 3: attention (transposed) fused with PV, per q-tile ----------
  {
    const float* bxh = bxT + wv * (kNP * kNP);
#pragma unroll
    for (int qt = 0; qt < 4; ++qt) {
      f32x4 S[4];
#pragma unroll
      for (int kt = 0; kt < 4; ++kt) {
        f32x4 z = {};
        S[kt] = __builtin_amdgcn_mfma_f32_16x16x32_bf16(Kf[kt], Qf[qt], z, 0, 0, 0);
      }
#pragma unroll
      for (int kt = 0; kt < 4; ++kt)
#pragma unroll
        for (int r = 0; r < 4; ++r)
          S[kt][r] += bxh[(kt * 16 + lg * 4 + r) * kNP + qt * 16 + ln];
      float m = S[0][0];
#pragma unroll
      for (int kt = 0; kt < 4; ++kt)
#pragma unroll
        for (int r = 0; r < 4; ++r) m = fmaxf(m, S[kt][r]);
      m = fmaxf(m, __shfl_xor(m, 16));
      m = fmaxf(m, __shfl_xor(m, 32));
      float s = 0.f;
#pragma unroll
      for (int kt = 0; kt < 4; ++kt)
#pragma unroll
        for (int r = 0; r < 4; ++r) {
          float p = __expf(S[kt][r] - m);
          S[kt][r] = p;
          s += p;
        }
      s += __shfl_xor(s, 16);
      s += __shfl_xor(s, 32);
      const float rv = 1.f / s;
      const s16x8 P0 = fragize(S[0], S[1], hi, srcbase);
      const s16x8 P1 = fragize(S[2], S[3], hi, srcbase);
#pragma unroll
      for (int dt = 0; dt < 2; ++dt) {
        f32x4 O = {};
        O = __builtin_amdgcn_mfma_f32_16x16x32_bf16(Vf[dt][0], P0, O, 0, 0, 0);
        O = __builtin_amdgcn_mfma_f32_16x16x32_bf16(Vf[dt][1], P1, O, 0, 0, 0);
        s16x4 pk;
#pragma unroll
        for (int r = 0; r < 4; ++r) pk[r] = f2b(O[r] * rv);
        *(s16x4*)&aoT[xoff(qt * 16 + ln, wv * 32 + dt * 16 + lg * 4)] = pk;
      }
    }
  }
  __syncthreads();
  __builtin_amdgcn_sched_barrier(0);

  // ---------- Phase 4: out = Wp @ attn_out + b ----------
#pragma unroll 1
  for (int i = 0; i < 2; ++i) {
    const int o0 = 32 * wv + 16 * i;
    f32x4 acc[4] = {};
    const short* WA = Wp + (size_t)(o0 + ln) * kC + lg * 8;
#pragma unroll
    for (int kk = 0; kk < 8; ++kk) {
      const s16x8 A = *(const s16x8*)&WA[kk * 32];
#pragma unroll
      for (int nt = 0; nt < 4; ++nt) {
        const s16x8 B = *(const s16x8*)&aoT[xoff(nt * 16 + ln, kk * 32 + lg * 8)];
        acc[nt] = __builtin_amdgcn_mfma_f32_16x16x32_bf16(A, B, acc[nt], 0, 0, 0);
      }
    }
    const f32x4 pb = *(const f32x4*)&proj_b[o0 + lg * 4];
#pragma unroll
    for (int nt = 0; nt < 4; ++nt) {
      const int n = nt * 16 + ln;
      if (n < kN) {
#pragma unroll
        for (int r = 0; r < 4; ++r)
          out[wbase + (size_t)(o0 + lg * 4 + r) * kN + n] = acc[nt][r] + pb[r];
      }
    }
  }
}

extern "C" void kernel_launch(void* const* d_in, const int* in_sizes, int n_in,
                              void* d_out, int out_size, void* d_ws, size_t ws_size,
                              hipStream_t stream) {
  (void)in_sizes; (void)n_in; (void)out_size; (void)ws_size;
  const float* x      = (const float*)d_in[0];
  const float* qkv_w  = (const float*)d_in[1];
  const float* qkv_b  = (const float*)d_in[2];
  const float* proj_w = (const float*)d_in[3];
  const float* proj_b = (const float*)d_in[4];
  const float* btab   = (const float*)d_in[5];
  const int*   ridx   = (const int*)d_in[6];

  short* Wq  = (short*)d_ws;                     // 393216 B
  short* Wp  = (short*)((char*)d_ws + 393216);   // 131072 B
  float* bxT = (float*)((char*)d_ws + 524288);   // 131072 B

  prep_kernel<<<768, 256, 0, stream>>>(qkv_w, proj_w, btab, ridx, Wq, Wp, bxT);
  winattn_kernel<<<2048, 512, 0, stream>>>(x, qkv_b, proj_b, Wq, Wp, bxT, (float*)d_out);
}

// Round 5
// 242.911 us; speedup vs baseline: 1.3809x; 1.3809x over previous
//
#include <hip/hip_runtime.h>

typedef float    f32x4 __attribute__((ext_vector_type(4)));
typedef short    s16x8 __attribute__((ext_vector_type(8)));
typedef short    s16x4 __attribute__((ext_vector_type(4)));
typedef unsigned u32x4 __attribute__((ext_vector_type(4)));

static __device__ __forceinline__ short f2b(float f) {
  unsigned u = __builtin_bit_cast(unsigned, f);
  u += 0x7fffu + ((u >> 16) & 1u);   // round-to-nearest-even
  return (short)(u >> 16);
}

// ---- problem constants ----
constexpr int kC  = 256;   // channels
constexpr int kN  = 49;    // tokens per window
constexpr int kNP = 64;    // padded tokens
constexpr float kScale = 0.17677669529663687f;  // 1/sqrt(32)

// Swizzled LDS offset (in shorts) for a [64 tokens][256 chan] bf16 tile.
static __device__ __forceinline__ int xoff(int n, int c) {
  return n * 256 + ((((c >> 3) ^ (n & 31)) << 3) | (c & 7));
}

// ws: Wq bf16 [768][256] @0, Wp bf16 [256][256] @393216, bxT f32 [8][64][64] @524288
__global__ void prep_kernel(const float* __restrict__ qw,
                            const float* __restrict__ pw,
                            const float* __restrict__ bt,
                            const int* __restrict__ ri,
                            short* __restrict__ Wq,
                            short* __restrict__ Wp,
                            float* __restrict__ bxT) {
  int i = blockIdx.x * 256 + threadIdx.x;
  if (i < 768 * 256) Wq[i] = f2b(qw[i]);
  if (i < 256 * 256) Wp[i] = f2b(pw[i]);
  if (i < 8 * 64 * 64) {                  // bxT[h][key][q], padding masked
    int h = i >> 12, k = (i >> 6) & 63, q = i & 63;
    float v = -10000.f;
    if (q < kN && k < kN) v = bt[ri[q * kN + k] * 8 + h];
    bxT[i] = v;
  }
}

// Build an MFMA A/B fragment (8 bf16, elem idx e = lg*8+j over a 32-block) from
// two f32x4 acc tiles: Ta holds elems 0..15, Tb 16..31, source layout
// elem = src_lg*4 + r at fixed ln.  (T12-style cvt_pk + lane shuffle.)
static __device__ __forceinline__ s16x8 fragize(f32x4 Ta, f32x4 Tb, int hi, int srcbase) {
  unsigned a0, a1, b0, b1;
  asm("v_cvt_pk_bf16_f32 %0, %1, %2" : "=v"(a0) : "v"(Ta[0]), "v"(Ta[1]));
  asm("v_cvt_pk_bf16_f32 %0, %1, %2" : "=v"(a1) : "v"(Ta[2]), "v"(Ta[3]));
  asm("v_cvt_pk_bf16_f32 %0, %1, %2" : "=v"(b0) : "v"(Tb[0]), "v"(Tb[1]));
  asm("v_cvt_pk_bf16_f32 %0, %1, %2" : "=v"(b1) : "v"(Tb[2]), "v"(Tb[3]));
  u32x4 fw;
#pragma unroll
  for (int j = 0; j < 4; ++j) {
    const int src = srcbase + (j >> 1) * 16;
    unsigned wa = __shfl((j & 1) ? a1 : a0, src);
    unsigned wb = __shfl((j & 1) ? b1 : b0, src);
    fw[j] = hi ? wb : wa;
  }
  return __builtin_bit_cast(s16x8, fw);
}

__global__ __launch_bounds__(512, 4) void winattn_kernel(
    const float* __restrict__ x, const float* __restrict__ qkv_b,
    const float* __restrict__ proj_b, const short* __restrict__ Wq,
    const short* __restrict__ Wp, const float* __restrict__ bxT,
    float* __restrict__ out) {
  __shared__ alignas(16) short xT[kNP * kC];    // 32768 B, alive phases 1-3
  __shared__ alignas(16) short aoT[kNP * kC];   // 32768 B, attn-out^T

  const int tid  = threadIdx.x;
  const int wv   = tid >> 6;           // wave = head
  const int lane = tid & 63;
  const int lg   = lane >> 4;
  const int ln   = lane & 15;
  const int hi   = lg >> 1;
  const int srcbase = (lg & 1) * 32 + ln;
  const size_t wbase = (size_t)blockIdx.x * (kC * kN);

  // ---------- Phase 1: stage x^T (bf16, swizzled) ----------
  {
    const float* xw = x + wbase;
    for (int i = tid; i < kC * kN; i += 512) {
      int c = i / kN, n = i - c * kN;
      xT[xoff(n, c)] = f2b(xw[i]);
    }
    for (int i = tid; i < (kNP - kN) * kC; i += 512) {
      int n = kN + (i >> 8), c = i & 255;
      xT[xoff(n, c)] = 0;
    }
  }
  __syncthreads();

  // ---------- Phase 2: per-head K (orig orientation) and V (swapped) -> regs ----------
  s16x8 Kf[4];       // K frags: row k-token, k-elems = d
  s16x8 Vf[2][2];    // V^T frags [dt][k2]: row d, k-elems = tokens

  {  // --- K section
    f32x4 acc0[4] = {}, acc1[4] = {};
    const short* WA = Wq + (size_t)(256 + 32 * wv + ln) * kC + lg * 8;
#pragma unroll 1
    for (int kk = 0; kk < 8; ++kk) {
      const s16x8 A0 = *(const s16x8*)&WA[kk * 32];
      const s16x8 A1 = *(const s16x8*)&WA[16 * kC + kk * 32];
#pragma unroll
      for (int nt = 0; nt < 4; ++nt) {
        const s16x8 B = *(const s16x8*)&xT[xoff(nt * 16 + ln, kk * 32 + lg * 8)];
        acc0[nt] = __builtin_amdgcn_mfma_f32_16x16x32_bf16(A0, B, acc0[nt], 0, 0, 0);
        acc1[nt] = __builtin_amdgcn_mfma_f32_16x16x32_bf16(A1, B, acc1[nt], 0, 0, 0);
      }
    }
    const f32x4 b0 = *(const f32x4*)&qkv_b[256 + 32 * wv + lg * 4];
    const f32x4 b1 = *(const f32x4*)&qkv_b[256 + 32 * wv + 16 + lg * 4];
#pragma unroll
    for (int nt = 0; nt < 4; ++nt) {
      f32x4 Ta, Tb;
#pragma unroll
      for (int r = 0; r < 4; ++r) {
        Ta[r] = acc0[nt][r] + b0[r];
        Tb[r] = acc1[nt][r] + b1[r];
      }
      Kf[nt] = fragize(Ta, Tb, hi, srcbase);
    }
  }
  __builtin_amdgcn_sched_barrier(0);

  {  // --- V section (swapped operands -> V^T accs)
    f32x4 accv[4][2] = {};
    const short* WA = Wq + (size_t)(512 + 32 * wv + ln) * kC + lg * 8;
#pragma unroll 1
    for (int kk = 0; kk < 8; ++kk) {
      const s16x8 A0 = *(const s16x8*)&WA[kk * 32];
      const s16x8 A1 = *(const s16x8*)&WA[16 * kC + kk * 32];
#pragma unroll
      for (int tt = 0; tt < 4; ++tt) {
        const s16x8 B = *(const s16x8*)&xT[xoff(tt * 16 + ln, kk * 32 + lg * 8)];
        accv[tt][0] = __builtin_amdgcn_mfma_f32_16x16x32_bf16(B, A0, accv[tt][0], 0, 0, 0);
        accv[tt][1] = __builtin_amdgcn_mfma_f32_16x16x32_bf16(B, A1, accv[tt][1], 0, 0, 0);
      }
    }
    const float bv0 = qkv_b[512 + 32 * wv + ln];
    const float bv1 = qkv_b[512 + 32 * wv + 16 + ln];
#pragma unroll
    for (int dt = 0; dt < 2; ++dt) {
      const float bv = dt ? bv1 : bv0;
#pragma unroll
      for (int k2 = 0; k2 < 2; ++k2) {
        f32x4 Ta, Tb;
#pragma unroll
        for (int r = 0; r < 4; ++r) {
          Ta[r] = accv[2 * k2][dt][r] + bv;
          Tb[r] = accv[2 * k2 + 1][dt][r] + bv;
        }
        Vf[dt][k2] = fragize(Ta, Tb, hi, srcbase);
      }
    }
  }
  __builtin_amdgcn_sched_barrier(0);

  // ---------- Phase 3: per q-tile: Q on the fly -> S^T -> softmax -> PV ----------
  {
    const float* bxh = bxT + wv * (kNP * kNP);
    const f32x4 qb0 = *(const f32x4*)&qkv_b[32 * wv + lg * 4];
    const f32x4 qb1 = *(const f32x4*)&qkv_b[32 * wv + 16 + lg * 4];
    const short* WA = Wq + (size_t)(32 * wv + ln) * kC + lg * 8;
#pragma unroll 1
    for (int qt = 0; qt < 4; ++qt) {
      // Q-tile GEMM (16 tokens)
      f32x4 qa0 = {}, qa1 = {};
#pragma unroll 1
      for (int kk = 0; kk < 8; ++kk) {
        const s16x8 A0 = *(const s16x8*)&WA[kk * 32];
        const s16x8 A1 = *(const s16x8*)&WA[16 * kC + kk * 32];
        const s16x8 B  = *(const s16x8*)&xT[xoff(qt * 16 + ln, kk * 32 + lg * 8)];
        qa0 = __builtin_amdgcn_mfma_f32_16x16x32_bf16(A0, B, qa0, 0, 0, 0);
        qa1 = __builtin_amdgcn_mfma_f32_16x16x32_bf16(A1, B, qa1, 0, 0, 0);
      }
      f32x4 Ta, Tb;
#pragma unroll
      for (int r = 0; r < 4; ++r) {
        Ta[r] = (qa0[r] + qb0[r]) * kScale;
        Tb[r] = (qa1[r] + qb1[r]) * kScale;
      }
      const s16x8 Qf = fragize(Ta, Tb, hi, srcbase);

      // S^T = K @ Q  (+bias), softmax over keys (in-lane + 2 shuffles)
      f32x4 S[4];
#pragma unroll
      for (int kt = 0; kt < 4; ++kt) {
        f32x4 z = {};
        S[kt] = __builtin_amdgcn_mfma_f32_16x16x32_bf16(Kf[kt], Qf, z, 0, 0, 0);
      }
#pragma unroll
      for (int kt = 0; kt < 4; ++kt)
#pragma unroll
        for (int r = 0; r < 4; ++r)
          S[kt][r] += bxh[(kt * 16 + lg * 4 + r) * kNP + qt * 16 + ln];
      float m = S[0][0];
#pragma unroll
      for (int kt = 0; kt < 4; ++kt)
#pragma unroll
        for (int r = 0; r < 4; ++r) m = fmaxf(m, S[kt][r]);
      m = fmaxf(m, __shfl_xor(m, 16));
      m = fmaxf(m, __shfl_xor(m, 32));
      float s = 0.f;
#pragma unroll
      for (int kt = 0; kt < 4; ++kt)
#pragma unroll
        for (int r = 0; r < 4; ++r) {
          float p = __expf(S[kt][r] - m);
          S[kt][r] = p;
          s += p;
        }
      s += __shfl_xor(s, 16);
      s += __shfl_xor(s, 32);
      const float rv = 1.f / s;
      const s16x8 P0 = fragize(S[0], S[1], hi, srcbase);
      const s16x8 P1 = fragize(S[2], S[3], hi, srcbase);
#pragma unroll
      for (int dt = 0; dt < 2; ++dt) {
        f32x4 O = {};
        O = __builtin_amdgcn_mfma_f32_16x16x32_bf16(Vf[dt][0], P0, O, 0, 0, 0);
        O = __builtin_amdgcn_mfma_f32_16x16x32_bf16(Vf[dt][1], P1, O, 0, 0, 0);
        s16x4 pk;
#pragma unroll
        for (int r = 0; r < 4; ++r) pk[r] = f2b(O[r] * rv);
        *(s16x4*)&aoT[xoff(qt * 16 + ln, wv * 32 + dt * 16 + lg * 4)] = pk;
      }
      __builtin_amdgcn_sched_barrier(0);
    }
  }
  __syncthreads();

  // ---------- Phase 4: out = Wp @ attn_out + b ----------
#pragma unroll 1
  for (int i = 0; i < 2; ++i) {
    const int o0 = 32 * wv + 16 * i;
    f32x4 acc[4] = {};
    const short* WA = Wp + (size_t)(o0 + ln) * kC + lg * 8;
#pragma unroll 1
    for (int kk = 0; kk < 8; ++kk) {
      const s16x8 A = *(const s16x8*)&WA[kk * 32];
#pragma unroll
      for (int nt = 0; nt < 4; ++nt) {
        const s16x8 B = *(const s16x8*)&aoT[xoff(nt * 16 + ln, kk * 32 + lg * 8)];
        acc[nt] = __builtin_amdgcn_mfma_f32_16x16x32_bf16(A, B, acc[nt], 0, 0, 0);
      }
    }
    const f32x4 pb = *(const f32x4*)&proj_b[o0 + lg * 4];
#pragma unroll
    for (int nt = 0; nt < 4; ++nt) {
      const int n = nt * 16 + ln;
      if (n < kN) {
#pragma unroll
        for (int r = 0; r < 4; ++r)
          out[wbase + (size_t)(o0 + lg * 4 + r) * kN + n] = acc[nt][r] + pb[r];
      }
    }
  }
}

extern "C" void kernel_launch(void* const* d_in, const int* in_sizes, int n_in,
                              void* d_out, int out_size, void* d_ws, size_t ws_size,
                              hipStream_t stream) {
  (void)in_sizes; (void)n_in; (void)out_size; (void)ws_size;
  const float* x      = (const float*)d_in[0];
  const float* qkv_w  = (const float*)d_in[1];
  const float* qkv_b  = (const float*)d_in[2];
  const float* proj_w = (const float*)d_in[3];
  const float* proj_b = (const float*)d_in[4];
  const float* btab   = (const float*)d_in[5];
  const int*   ridx   = (const int*)d_in[6];

  short* Wq  = (short*)d_ws;                     // 393216 B
  short* Wp  = (short*)((char*)d_ws + 393216);   // 131072 B
  float* bxT = (float*)((char*)d_ws + 524288);   // 131072 B

  prep_kernel<<<768, 256, 0, stream>>>(qkv_w, proj_w, btab, ridx, Wq, Wp, bxT);
  winattn_kernel<<<2048, 512, 0, stream>>>(x, qkv_b, proj_b, Wq, Wp, bxT, (float*)d_out);
}

// Round 6
// 239.042 us; speedup vs baseline: 1.4032x; 1.0162x over previous
//
#include <hip/hip_runtime.h>

typedef float    f32x4 __attribute__((ext_vector_type(4)));
typedef short    s16x8 __attribute__((ext_vector_type(8)));
typedef short    s16x4 __attribute__((ext_vector_type(4)));
typedef unsigned u32x4 __attribute__((ext_vector_type(4)));

static __device__ __forceinline__ short f2b(float f) {
  unsigned u = __builtin_bit_cast(unsigned, f);
  u += 0x7fffu + ((u >> 16) & 1u);   // round-to-nearest-even
  return (short)(u >> 16);
}

// ---- problem constants ----
constexpr int kC  = 256;   // channels
constexpr int kN  = 49;    // tokens per window
constexpr int kNP = 64;    // padded tokens
constexpr float kScale = 0.17677669529663687f;  // 1/sqrt(32)

// Swizzled LDS offset (in shorts) for a [64 tokens][256 chan] bf16 tile.
static __device__ __forceinline__ int xoff(int n, int c) {
  return n * 256 + ((((c >> 3) ^ (n & 31)) << 3) | (c & 7));
}

// ws: Wq bf16 [768][256] @0, Wp bf16 [256][256] @393216, bxT f32 [8][64][64] @524288
__global__ void prep_kernel(const float* __restrict__ qw,
                            const float* __restrict__ pw,
                            const float* __restrict__ bt,
                            const int* __restrict__ ri,
                            short* __restrict__ Wq,
                            short* __restrict__ Wp,
                            float* __restrict__ bxT) {
  int i = blockIdx.x * 256 + threadIdx.x;
  if (i < 768 * 256) Wq[i] = f2b(qw[i]);
  if (i < 256 * 256) Wp[i] = f2b(pw[i]);
  if (i < 8 * 64 * 64) {                  // bxT[h][key][q], padding masked
    int h = i >> 12, k = (i >> 6) & 63, q = i & 63;
    float v = -10000.f;
    if (q < kN && k < kN) v = bt[ri[q * kN + k] * 8 + h];
    bxT[i] = v;
  }
}

// Build an MFMA A/B fragment (8 bf16, elem idx e = lg*8+j over a 32-block) from
// two f32x4 acc tiles: Ta holds elems 0..15, Tb 16..31, source layout
// elem = src_lg*4 + r at fixed ln.  (T12-style cvt_pk + lane shuffle.)
static __device__ __forceinline__ s16x8 fragize(f32x4 Ta, f32x4 Tb, int hi, int srcbase) {
  unsigned a0, a1, b0, b1;
  asm("v_cvt_pk_bf16_f32 %0, %1, %2" : "=v"(a0) : "v"(Ta[0]), "v"(Ta[1]));
  asm("v_cvt_pk_bf16_f32 %0, %1, %2" : "=v"(a1) : "v"(Ta[2]), "v"(Ta[3]));
  asm("v_cvt_pk_bf16_f32 %0, %1, %2" : "=v"(b0) : "v"(Tb[0]), "v"(Tb[1]));
  asm("v_cvt_pk_bf16_f32 %0, %1, %2" : "=v"(b1) : "v"(Tb[2]), "v"(Tb[3]));
  u32x4 fw;
#pragma unroll
  for (int j = 0; j < 4; ++j) {
    const int src = srcbase + (j >> 1) * 16;
    unsigned wa = __shfl((j & 1) ? a1 : a0, src);
    unsigned wb = __shfl((j & 1) ? b1 : b0, src);
    fw[j] = hi ? wb : wa;
  }
  return __builtin_bit_cast(s16x8, fw);
}

__global__ __launch_bounds__(512, 4) void winattn_kernel(
    const float* __restrict__ x, const float* __restrict__ qkv_b,
    const float* __restrict__ proj_b, const short* __restrict__ Wq,
    const short* __restrict__ Wp, const float* __restrict__ bxT,
    float* __restrict__ out) {
  __shared__ alignas(16) short xT[kNP * kC];    // 32768 B, alive phases 1-3
  __shared__ alignas(16) short aoT[kNP * kC];   // 32768 B, attn-out^T

  const int tid  = threadIdx.x;
  const int wv   = tid >> 6;           // wave = head
  const int lane = tid & 63;
  const int lg   = lane >> 4;
  const int ln   = lane & 15;
  const int hi   = lg >> 1;
  const int srcbase = (lg & 1) * 32 + ln;
  const size_t wbase = (size_t)blockIdx.x * (kC * kN);

  // ---------- Phase 1: stage x^T (bf16, swizzled) ----------
  {
    const float* xw = x + wbase;
    for (int i = tid; i < kC * kN; i += 512) {
      int c = i / kN, n = i - c * kN;
      xT[xoff(n, c)] = f2b(xw[i]);
    }
    for (int i = tid; i < (kNP - kN) * kC; i += 512) {
      int n = kN + (i >> 8), c = i & 255;
      xT[xoff(n, c)] = 0;
    }
  }
  __syncthreads();

  // ---------- Phase 2: per-head K (orig orientation) and V (swapped) -> regs ----------
  s16x8 Kf[4];       // K frags: row k-token, k-elems = d
  s16x8 Vf[2][2];    // V^T frags [dt][k2]: row d, k-elems = tokens

  {  // --- K section
    f32x4 acc0[4] = {}, acc1[4] = {};
    const short* WA = Wq + (size_t)(256 + 32 * wv + ln) * kC + lg * 8;
#pragma unroll 4
    for (int kk = 0; kk < 8; ++kk) {
      const s16x8 A0 = *(const s16x8*)&WA[kk * 32];
      const s16x8 A1 = *(const s16x8*)&WA[16 * kC + kk * 32];
#pragma unroll
      for (int nt = 0; nt < 4; ++nt) {
        const s16x8 B = *(const s16x8*)&xT[xoff(nt * 16 + ln, kk * 32 + lg * 8)];
        acc0[nt] = __builtin_amdgcn_mfma_f32_16x16x32_bf16(A0, B, acc0[nt], 0, 0, 0);
        acc1[nt] = __builtin_amdgcn_mfma_f32_16x16x32_bf16(A1, B, acc1[nt], 0, 0, 0);
      }
    }
    const f32x4 b0 = *(const f32x4*)&qkv_b[256 + 32 * wv + lg * 4];
    const f32x4 b1 = *(const f32x4*)&qkv_b[256 + 32 * wv + 16 + lg * 4];
#pragma unroll
    for (int nt = 0; nt < 4; ++nt) {
      f32x4 Ta, Tb;
#pragma unroll
      for (int r = 0; r < 4; ++r) {
        Ta[r] = acc0[nt][r] + b0[r];
        Tb[r] = acc1[nt][r] + b1[r];
      }
      Kf[nt] = fragize(Ta, Tb, hi, srcbase);
    }
  }
  __builtin_amdgcn_sched_barrier(0);

  {  // --- V section (swapped operands -> V^T accs)
    f32x4 accv[4][2] = {};
    const short* WA = Wq + (size_t)(512 + 32 * wv + ln) * kC + lg * 8;
#pragma unroll 4
    for (int kk = 0; kk < 8; ++kk) {
      const s16x8 A0 = *(const s16x8*)&WA[kk * 32];
      const s16x8 A1 = *(const s16x8*)&WA[16 * kC + kk * 32];
#pragma unroll
      for (int tt = 0; tt < 4; ++tt) {
        const s16x8 B = *(const s16x8*)&xT[xoff(tt * 16 + ln, kk * 32 + lg * 8)];
        accv[tt][0] = __builtin_amdgcn_mfma_f32_16x16x32_bf16(B, A0, accv[tt][0], 0, 0, 0);
        accv[tt][1] = __builtin_amdgcn_mfma_f32_16x16x32_bf16(B, A1, accv[tt][1], 0, 0, 0);
      }
    }
    const float bv0 = qkv_b[512 + 32 * wv + ln];
    const float bv1 = qkv_b[512 + 32 * wv + 16 + ln];
#pragma unroll
    for (int dt = 0; dt < 2; ++dt) {
      const float bv = dt ? bv1 : bv0;
#pragma unroll
      for (int k2 = 0; k2 < 2; ++k2) {
        f32x4 Ta, Tb;
#pragma unroll
        for (int r = 0; r < 4; ++r) {
          Ta[r] = accv[2 * k2][dt][r] + bv;
          Tb[r] = accv[2 * k2 + 1][dt][r] + bv;
        }
        Vf[dt][k2] = fragize(Ta, Tb, hi, srcbase);
      }
    }
  }
  __builtin_amdgcn_sched_barrier(0);

  // ---------- Phase 3: per q-tile: Q on the fly -> S^T -> softmax -> PV ----------
  {
    const float* bxh = bxT + wv * (kNP * kNP);
    const f32x4 qb0 = *(const f32x4*)&qkv_b[32 * wv + lg * 4];
    const f32x4 qb1 = *(const f32x4*)&qkv_b[32 * wv + 16 + lg * 4];
    const short* WA = Wq + (size_t)(32 * wv + ln) * kC + lg * 8;
#pragma unroll 2
    for (int qt = 0; qt < 4; ++qt) {
      // Q-tile GEMM (16 tokens)
      f32x4 qa0 = {}, qa1 = {};
#pragma unroll 4
      for (int kk = 0; kk < 8; ++kk) {
        const s16x8 A0 = *(const s16x8*)&WA[kk * 32];
        const s16x8 A1 = *(const s16x8*)&WA[16 * kC + kk * 32];
        const s16x8 B  = *(const s16x8*)&xT[xoff(qt * 16 + ln, kk * 32 + lg * 8)];
        qa0 = __builtin_amdgcn_mfma_f32_16x16x32_bf16(A0, B, qa0, 0, 0, 0);
        qa1 = __builtin_amdgcn_mfma_f32_16x16x32_bf16(A1, B, qa1, 0, 0, 0);
      }
      f32x4 Ta, Tb;
#pragma unroll
      for (int r = 0; r < 4; ++r) {
        Ta[r] = (qa0[r] + qb0[r]) * kScale;
        Tb[r] = (qa1[r] + qb1[r]) * kScale;
      }
      const s16x8 Qf = fragize(Ta, Tb, hi, srcbase);

      // S^T = K @ Q  (+bias), softmax over keys (in-lane + 2 shuffles)
      f32x4 S[4];
#pragma unroll
      for (int kt = 0; kt < 4; ++kt) {
        f32x4 z = {};
        S[kt] = __builtin_amdgcn_mfma_f32_16x16x32_bf16(Kf[kt], Qf, z, 0, 0, 0);
      }
#pragma unroll
      for (int kt = 0; kt < 4; ++kt)
#pragma unroll
        for (int r = 0; r < 4; ++r)
          S[kt][r] += bxh[(kt * 16 + lg * 4 + r) * kNP + qt * 16 + ln];
      float m = S[0][0];
#pragma unroll
      for (int kt = 0; kt < 4; ++kt)
#pragma unroll
        for (int r = 0; r < 4; ++r) m = fmaxf(m, S[kt][r]);
      m = fmaxf(m, __shfl_xor(m, 16));
      m = fmaxf(m, __shfl_xor(m, 32));
      float s = 0.f;
#pragma unroll
      for (int kt = 0; kt < 4; ++kt)
#pragma unroll
        for (int r = 0; r < 4; ++r) {
          float p = __expf(S[kt][r] - m);
          S[kt][r] = p;
          s += p;
        }
      s += __shfl_xor(s, 16);
      s += __shfl_xor(s, 32);
      const float rv = 1.f / s;
      const s16x8 P0 = fragize(S[0], S[1], hi, srcbase);
      const s16x8 P1 = fragize(S[2], S[3], hi, srcbase);
#pragma unroll
      for (int dt = 0; dt < 2; ++dt) {
        f32x4 O = {};
        O = __builtin_amdgcn_mfma_f32_16x16x32_bf16(Vf[dt][0], P0, O, 0, 0, 0);
        O = __builtin_amdgcn_mfma_f32_16x16x32_bf16(Vf[dt][1], P1, O, 0, 0, 0);
        s16x4 pk;
#pragma unroll
        for (int r = 0; r < 4; ++r) pk[r] = f2b(O[r] * rv);
        *(s16x4*)&aoT[xoff(qt * 16 + ln, wv * 32 + dt * 16 + lg * 4)] = pk;
      }
    }
  }
  __syncthreads();

  // ---------- Phase 4: out = Wp @ attn_out + b ----------
#pragma unroll 1
  for (int i = 0; i < 2; ++i) {
    const int o0 = 32 * wv + 16 * i;
    f32x4 acc[4] = {};
    const short* WA = Wp + (size_t)(o0 + ln) * kC + lg * 8;
#pragma unroll 4
    for (int kk = 0; kk < 8; ++kk) {
      const s16x8 A = *(const s16x8*)&WA[kk * 32];
#pragma unroll
      for (int nt = 0; nt < 4; ++nt) {
        const s16x8 B = *(const s16x8*)&aoT[xoff(nt * 16 + ln, kk * 32 + lg * 8)];
        acc[nt] = __builtin_amdgcn_mfma_f32_16x16x32_bf16(A, B, acc[nt], 0, 0, 0);
      }
    }
    const f32x4 pb = *(const f32x4*)&proj_b[o0 + lg * 4];
#pragma unroll
    for (int nt = 0; nt < 4; ++nt) {
      const int n = nt * 16 + ln;
      if (n < kN) {
#pragma unroll
        for (int r = 0; r < 4; ++r)
          out[wbase + (size_t)(o0 + lg * 4 + r) * kN + n] = acc[nt][r] + pb[r];
      }
    }
  }
}

extern "C" void kernel_launch(void* const* d_in, const int* in_sizes, int n_in,
                              void* d_out, int out_size, void* d_ws, size_t ws_size,
                              hipStream_t stream) {
  (void)in_sizes; (void)n_in; (void)out_size; (void)ws_size;
  const float* x      = (const float*)d_in[0];
  const float* qkv_w  = (const float*)d_in[1];
  const float* qkv_b  = (const float*)d_in[2];
  const float* proj_w = (const float*)d_in[3];
  const float* proj_b = (const float*)d_in[4];
  const float* btab   = (const float*)d_in[5];
  const int*   ridx   = (const int*)d_in[6];

  short* Wq  = (short*)d_ws;                     // 393216 B
  short* Wp  = (short*)((char*)d_ws + 393216);   // 131072 B
  float* bxT = (float*)((char*)d_ws + 524288);   // 131072 B

  prep_kernel<<<768, 256, 0, stream>>>(qkv_w, proj_w, btab, ridx, Wq, Wp, bxT);
  winattn_kernel<<<2048, 512, 0, stream>>>(x, qkv_b, proj_b, Wq, Wp, bxT, (float*)d_out);
}

// Round 9
// 236.814 us; speedup vs baseline: 1.4164x; 1.0094x over previous
//
#include <hip/hip_runtime.h>

typedef float    f32x4 __attribute__((ext_vector_type(4)));
typedef short    s16x8 __attribute__((ext_vector_type(8)));
typedef short    s16x4 __attribute__((ext_vector_type(4)));
typedef unsigned u32x4 __attribute__((ext_vector_type(4)));

static __device__ __forceinline__ short f2b(float f) {
  unsigned u = __builtin_bit_cast(unsigned, f);
  u += 0x7fffu + ((u >> 16) & 1u);   // round-to-nearest-even
  return (short)(u >> 16);
}

// ---- problem constants ----
constexpr int kC  = 256;   // channels
constexpr int kN  = 49;    // tokens per window
constexpr int kNP = 64;    // padded tokens
constexpr float kScale = 0.17677669529663687f;  // 1/sqrt(32)

// Swizzled LDS offset (in shorts) for a [64 tokens][256 chan] bf16 tile.
static __device__ __forceinline__ int xoff(int n, int c) {
  return n * 256 + ((((c >> 3) ^ (n & 31)) << 3) | (c & 7));
}

// ws: Wq bf16 [768][256] @0, Wp bf16 [256][256] @393216, bxT f32 [8][64][64] @524288
__global__ void prep_kernel(const float* __restrict__ qw,
                            const float* __restrict__ pw,
                            const float* __restrict__ bt,
                            const int* __restrict__ ri,
                            short* __restrict__ Wq,
                            short* __restrict__ Wp,
                            float* __restrict__ bxT) {
  int i = blockIdx.x * 256 + threadIdx.x;
  if (i < 768 * 256) Wq[i] = f2b(qw[i]);
  if (i < 256 * 256) Wp[i] = f2b(pw[i]);
  if (i < 8 * 64 * 64) {                  // bxT[h][key][q], padding masked
    int h = i >> 12, k = (i >> 6) & 63, q = i & 63;
    float v = -10000.f;
    if (q < kN && k < kN) v = bt[ri[q * kN + k] * 8 + h];
    bxT[i] = v;
  }
}

// Build an MFMA A/B fragment (8 bf16, elem idx e = lg*8+j over a 32-block) from
// two f32x4 acc tiles: Ta holds elems 0..15, Tb 16..31, source layout
// elem = src_lg*4 + r at fixed ln.  (T12-style cvt_pk + lane shuffle.)
// cvt_pk packing is self-consistent here: fragize outputs only ever meet other
// fragize outputs in an MFMA (QK^T, PV), so any within-pair order cancels.
static __device__ __forceinline__ s16x8 fragize(f32x4 Ta, f32x4 Tb, int hi, int srcbase) {
  unsigned a0, a1, b0, b1;
  asm("v_cvt_pk_bf16_f32 %0, %1, %2" : "=v"(a0) : "v"(Ta[0]), "v"(Ta[1]));
  asm("v_cvt_pk_bf16_f32 %0, %1, %2" : "=v"(a1) : "v"(Ta[2]), "v"(Ta[3]));
  asm("v_cvt_pk_bf16_f32 %0, %1, %2" : "=v"(b0) : "v"(Tb[0]), "v"(Tb[1]));
  asm("v_cvt_pk_bf16_f32 %0, %1, %2" : "=v"(b1) : "v"(Tb[2]), "v"(Tb[3]));
  u32x4 fw;
#pragma unroll
  for (int j = 0; j < 4; ++j) {
    const int src = srcbase + (j >> 1) * 16;
    unsigned wa = __shfl((j & 1) ? a1 : a0, src);
    unsigned wb = __shfl((j & 1) ? b1 : b0, src);
    fw[j] = hi ? wb : wa;
  }
  return __builtin_bit_cast(s16x8, fw);
}

__global__ __launch_bounds__(512, 4) void winattn_kernel(
    const float* __restrict__ x, const float* __restrict__ qkv_b,
    const float* __restrict__ proj_b, const short* __restrict__ Wq,
    const short* __restrict__ Wp, const float* __restrict__ bxT,
    float* __restrict__ out) {
  __shared__ alignas(16) short xT[kNP * kC];    // 32768 B, alive phases 1-3
  __shared__ alignas(16) short aoT[kNP * kC];   // 32768 B, attn-out^T

  const int tid  = threadIdx.x;
  const int wv   = tid >> 6;           // wave = head
  const int lane = tid & 63;
  const int lg   = lane >> 4;
  const int ln   = lane & 15;
  const int hi   = lg >> 1;
  const int srcbase = (lg & 1) * 32 + ln;
  const size_t wbase = (size_t)blockIdx.x * (kC * kN);

  // ---------- Phase 1: stage x^T: coalesced loads + f2b + short-vector b128 writes ----------
  {
    const float* xw = x + wbase;
    const int n = lane;                 // token = lane
#pragma unroll 1
    for (int it = 0; it < 4; ++it) {
      const int cb = it * 8 + wv;       // c-block (8 chans) 0..31
      s16x8 pk;
#pragma unroll
      for (int j = 0; j < 8; ++j)
        pk[j] = f2b((n < kN) ? xw[(cb * 8 + j) * kN + n] : 0.f);
      *(s16x8*)&xT[xoff(n, cb * 8)] = pk;   // short-based store (same TBAA as reads)
    }
  }
  __syncthreads();

  // ---------- Phase 2: per-head K (orig orientation) and V (swapped) -> regs ----------
  s16x8 Kf[4];       // K frags: row k-token, k-elems = d
  s16x8 Vf[2][2];    // V^T frags [dt][k2]: row d, k-elems = tokens

  {  // --- K section
    f32x4 acc0[4] = {}, acc1[4] = {};
    const short* WA = Wq + (size_t)(256 + 32 * wv + ln) * kC + lg * 8;
#pragma unroll 4
    for (int kk = 0; kk < 8; ++kk) {
      const s16x8 A0 = *(const s16x8*)&WA[kk * 32];
      const s16x8 A1 = *(const s16x8*)&WA[16 * kC + kk * 32];
#pragma unroll
      for (int nt = 0; nt < 4; ++nt) {
        const s16x8 B = *(const s16x8*)&xT[xoff(nt * 16 + ln, kk * 32 + lg * 8)];
        acc0[nt] = __builtin_amdgcn_mfma_f32_16x16x32_bf16(A0, B, acc0[nt], 0, 0, 0);
        acc1[nt] = __builtin_amdgcn_mfma_f32_16x16x32_bf16(A1, B, acc1[nt], 0, 0, 0);
      }
    }
    const f32x4 b0 = *(const f32x4*)&qkv_b[256 + 32 * wv + lg * 4];
    const f32x4 b1 = *(const f32x4*)&qkv_b[256 + 32 * wv + 16 + lg * 4];
#pragma unroll
    for (int nt = 0; nt < 4; ++nt) {
      f32x4 Ta, Tb;
#pragma unroll
      for (int r = 0; r < 4; ++r) {
        Ta[r] = acc0[nt][r] + b0[r];
        Tb[r] = acc1[nt][r] + b1[r];
      }
      Kf[nt] = fragize(Ta, Tb, hi, srcbase);
    }
  }
  __builtin_amdgcn_sched_barrier(0);

  {  // --- V section (swapped operands -> V^T accs)
    f32x4 accv[4][2] = {};
    const short* WA = Wq + (size_t)(512 + 32 * wv + ln) * kC + lg * 8;
#pragma unroll 4
    for (int kk = 0; kk < 8; ++kk) {
      const s16x8 A0 = *(const s16x8*)&WA[kk * 32];
      const s16x8 A1 = *(const s16x8*)&WA[16 * kC + kk * 32];
#pragma unroll
      for (int tt = 0; tt < 4; ++tt) {
        const s16x8 B = *(const s16x8*)&xT[xoff(tt * 16 + ln, kk * 32 + lg * 8)];
        accv[tt][0] = __builtin_amdgcn_mfma_f32_16x16x32_bf16(B, A0, accv[tt][0], 0, 0, 0);
        accv[tt][1] = __builtin_amdgcn_mfma_f32_16x16x32_bf16(B, A1, accv[tt][1], 0, 0, 0);
      }
    }
    const float bv0 = qkv_b[512 + 32 * wv + ln];
    const float bv1 = qkv_b[512 + 32 * wv + 16 + ln];
#pragma unroll
    for (int dt = 0; dt < 2; ++dt) {
      const float bv = dt ? bv1 : bv0;
#pragma unroll
      for (int k2 = 0; k2 < 2; ++k2) {
        f32x4 Ta, Tb;
#pragma unroll
        for (int r = 0; r < 4; ++r) {
          Ta[r] = accv[2 * k2][dt][r] + bv;
          Tb[r] = accv[2 * k2 + 1][dt][r] + bv;
        }
        Vf[dt][k2] = fragize(Ta, Tb, hi, srcbase);
      }
    }
  }
  __builtin_amdgcn_sched_barrier(0);

  // ---------- Phase 3: per q-tile: Q on the fly -> S^T -> softmax -> PV (R6 exact) ----------
  {
    const float* bxh = bxT + wv * (kNP * kNP);
    const f32x4 qb0 = *(const f32x4*)&qkv_b[32 * wv + lg * 4];
    const f32x4 qb1 = *(const f32x4*)&qkv_b[32 * wv + 16 + lg * 4];
    const short* WA = Wq + (size_t)(32 * wv + ln) * kC + lg * 8;
#pragma unroll 2
    for (int qt = 0; qt < 4; ++qt) {
      // Q-tile GEMM (16 tokens)
      f32x4 qa0 = {}, qa1 = {};
#pragma unroll 4
      for (int kk = 0; kk < 8; ++kk) {
        const s16x8 A0 = *(const s16x8*)&WA[kk * 32];
        const s16x8 A1 = *(const s16x8*)&WA[16 * kC + kk * 32];
        const s16x8 B  = *(const s16x8*)&xT[xoff(qt * 16 + ln, kk * 32 + lg * 8)];
        qa0 = __builtin_amdgcn_mfma_f32_16x16x32_bf16(A0, B, qa0, 0, 0, 0);
        qa1 = __builtin_amdgcn_mfma_f32_16x16x32_bf16(A1, B, qa1, 0, 0, 0);
      }
      f32x4 Ta, Tb;
#pragma unroll
      for (int r = 0; r < 4; ++r) {
        Ta[r] = (qa0[r] + qb0[r]) * kScale;
        Tb[r] = (qa1[r] + qb1[r]) * kScale;
      }
      const s16x8 Qf = fragize(Ta, Tb, hi, srcbase);

      // S^T = K @ Q  (+bias), softmax over keys (in-lane + 2 shuffles)
      f32x4 S[4];
#pragma unroll
      for (int kt = 0; kt < 4; ++kt) {
        f32x4 z = {};
        S[kt] = __builtin_amdgcn_mfma_f32_16x16x32_bf16(Kf[kt], Qf, z, 0, 0, 0);
      }
#pragma unroll
      for (int kt = 0; kt < 4; ++kt)
#pragma unroll
        for (int r = 0; r < 4; ++r)
          S[kt][r] += bxh[(kt * 16 + lg * 4 + r) * kNP + qt * 16 + ln];
      float m = S[0][0];
#pragma unroll
      for (int kt = 0; kt < 4; ++kt)
#pragma unroll
        for (int r = 0; r < 4; ++r) m = fmaxf(m, S[kt][r]);
      m = fmaxf(m, __shfl_xor(m, 16));
      m = fmaxf(m, __shfl_xor(m, 32));
      float s = 0.f;
#pragma unroll
      for (int kt = 0; kt < 4; ++kt)
#pragma unroll
        for (int r = 0; r < 4; ++r) {
          float p = __expf(S[kt][r] - m);
          S[kt][r] = p;
          s += p;
        }
      s += __shfl_xor(s, 16);
      s += __shfl_xor(s, 32);
      const float rv = 1.f / s;
      const s16x8 P0 = fragize(S[0], S[1], hi, srcbase);
      const s16x8 P1 = fragize(S[2], S[3], hi, srcbase);
#pragma unroll
      for (int dt = 0; dt < 2; ++dt) {
        f32x4 O = {};
        O = __builtin_amdgcn_mfma_f32_16x16x32_bf16(Vf[dt][0], P0, O, 0, 0, 0);
        O = __builtin_amdgcn_mfma_f32_16x16x32_bf16(Vf[dt][1], P1, O, 0, 0, 0);
        s16x4 pk;
#pragma unroll
        for (int r = 0; r < 4; ++r) pk[r] = f2b(O[r] * rv);
        *(s16x4*)&aoT[xoff(qt * 16 + ln, wv * 32 + dt * 16 + lg * 4)] = pk;
      }
    }
  }
  __syncthreads();

  // ---------- Phase 4: out = Wp @ attn_out + b (both row-groups share B reads) ----------
  {
    f32x4 acc[2][4] = {};
    const short* WA = Wp + (size_t)(32 * wv + ln) * kC + lg * 8;
#pragma unroll 4
    for (int kk = 0; kk < 8; ++kk) {
      const s16x8 A0 = *(const s16x8*)&WA[kk * 32];
      const s16x8 A1 = *(const s16x8*)&WA[16 * kC + kk * 32];
#pragma unroll
      for (int nt = 0; nt < 4; ++nt) {
        const s16x8 B = *(const s16x8*)&aoT[xoff(nt * 16 + ln, kk * 32 + lg * 8)];
        acc[0][nt] = __builtin_amdgcn_mfma_f32_16x16x32_bf16(A0, B, acc[0][nt], 0, 0, 0);
        acc[1][nt] = __builtin_amdgcn_mfma_f32_16x16x32_bf16(A1, B, acc[1][nt], 0, 0, 0);
      }
    }
#pragma unroll
    for (int i = 0; i < 2; ++i) {
      const int o0 = 32 * wv + 16 * i;
      const f32x4 pb = *(const f32x4*)&proj_b[o0 + lg * 4];
#pragma unroll
      for (int nt = 0; nt < 4; ++nt) {
        const int n = nt * 16 + ln;
        if (n < kN) {
#pragma unroll
          for (int r = 0; r < 4; ++r)
            out[wbase + (size_t)(o0 + lg * 4 + r) * kN + n] = acc[i][nt][r] + pb[r];
        }
      }
    }
  }
}

extern "C" void kernel_launch(void* const* d_in, const int* in_sizes, int n_in,
                              void* d_out, int out_size, void* d_ws, size_t ws_size,
                              hipStream_t stream) {
  (void)in_sizes; (void)n_in; (void)out_size; (void)ws_size;
  const float* x      = (const float*)d_in[0];
  const float* qkv_w  = (const float*)d_in[1];
  const float* qkv_b  = (const float*)d_in[2];
  const float* proj_w = (const float*)d_in[3];
  const float* proj_b = (const float*)d_in[4];
  const float* btab   = (const float*)d_in[5];
  const int*   ridx   = (const int*)d_in[6];

  short* Wq  = (short*)d_ws;                     // 393216 B
  short* Wp  = (short*)((char*)d_ws + 393216);   // 131072 B
  float* bxT = (float*)((char*)d_ws + 524288);   // 131072 B

  prep_kernel<<<768, 256, 0, stream>>>(qkv_w, proj_w, btab, ridx, Wq, Wp, bxT);
  winattn_kernel<<<2048, 512, 0, stream>>>(x, qkv_b, proj_b, Wq, Wp, bxT, (float*)d_out);
}